// Round 7
// baseline (300.552 us; speedup 1.0000x reference)
//
#include <hip/hip_runtime.h>
#include <cstdint>
#include <cstddef>

// VQ-VAE quantization forward, MI355X/gfx950 — bf16 split-precision MFMA version.
// dot(x, e_norm) = xh*eh + xh*el + xl*eh  (3x mfma_f32_16x16x32_bf16, fp32 accum)
//
// v8 = v7 with LDS pool reordered so all ds_read/ds_write offset immediates fit
// 16-bit unsigned (v7 compile error: X region at 65536+ overran offset field).
//   pool: [0,16384) X[2] (q*8192 = [hi 4K][lo 4K]);
//         [16384,81920) bbuf[2] (16384 + p*32768 + w*8192 = [hi 4K][lo 4K])
//
// v7 design: one-chunk-deep register pipeline (frags(c) prefetched during c-1;
// pass1 issues with zero wait), B dbuf 2x32KB, X dbuf 2x8KB, 80KB pool exact,
// counted vmcnt invariants, 2 dispatches (normalize zero-inits stats; final
// scalars via last-block ticket inside vq_main), post-loop vmcnt(0) drain with
// register keep-alive (v5 lesson).

typedef __attribute__((ext_vector_type(8))) short short8;
typedef __attribute__((ext_vector_type(4))) float f32x4;

namespace {
constexpr int kNT = 25600;           // N*T rows
constexpr int kD  = 1024;            // feature dim
constexpr int kM  = 256;             // codebook size
constexpr size_t kQElems = (size_t)kNT * kD;

// ws layout (float units). Codebook images: 32 chunks x [n=256][k=32] bf16,
// 16B sub-blocks swizzled: element idx = c*8192 + n*32 + (g ^ ((n>>1)&3))*8 + (k&7)
constexpr int WS_IMG_H = 0;                    // 262144 ushort = 131072 floats
constexpr int WS_IMG_L = 131072;               // 262144 ushort
constexpr int WS_E2N   = 262144;               // ||e_norm||^2 (256)
constexpr int WS_SCL   = WS_E2N + kM;          // ||e_raw|| + 1e-4 (256)
constexpr int WS_E2R   = WS_SCL + kM;          // ||e_raw||^2 (256)
constexpr int WS_COM   = WS_E2R + kM;          // commitment accumulator (4 floats)
constexpr int WS_HIST  = WS_COM + 4;           // histogram 256 ints
constexpr int WS_TICKET = WS_HIST + kM;        // last-block ticket (1 int)
}

typedef __attribute__((address_space(3))) unsigned int        lds_u32;
typedef const __attribute__((address_space(1))) unsigned int  glb_u32;
typedef const __attribute__((address_space(3))) char          lds_chc;

__device__ __forceinline__ void gl2lds16(const void* g, void* l) {
  __builtin_amdgcn_global_load_lds((glb_u32*)g, (lds_u32*)l, 16, 0, 0);
}

// inline-asm LDS read/write: compile-time offset immediate (16-bit unsigned!);
// lgkmcnt counted manually (rule #18: counted wait + sched_barrier(0)).
template <int OFF>
__device__ __forceinline__ short8 ldsr(lds_chc* p) {
  static_assert(OFF >= 0 && OFF < 65536, "ds offset immediate");
  short8 r;
  asm volatile("ds_read_b128 %0, %1 offset:%c2" : "=v"(r) : "v"(p), "i"(OFF));
  return r;
}
template <int OFF>
__device__ __forceinline__ void ldsw(lds_chc* p, short8 v) {
  static_assert(OFF >= 0 && OFF < 65536, "ds offset immediate");
  asm volatile("ds_write_b128 %0, %1 offset:%c2" :: "v"(p), "v"(v), "i"(OFF) : "memory");
}
// asm global load: keeps x-loads out of the compiler's vmcnt bookkeeping so our
// counted waits stay exact.
__device__ __forceinline__ f32x4 gld4(const float* p) {
  f32x4 r;
  asm volatile("global_load_dwordx4 %0, %1, off" : "=v"(r) : "v"(p));
  return r;
}

// ---------------- kernel 1: normalize codebook -> swizzled bf16 hi/lo images + stats ----
__global__ __launch_bounds__(256) void vq_normalize(const float* __restrict__ emb,
                                                    float* __restrict__ ws) {
  const int m = blockIdx.x;
  const int t = threadIdx.x;

  // zero-init stats (replaces hipMemsetAsync dispatch)
  if (t == 0) ((int*)(ws + WS_HIST))[m] = 0;
  if (m == 0 && t < 4) ws[WS_COM + t] = 0.0f;
  if (m == 0 && t == 4) ((int*)(ws + WS_TICKET))[0] = 0;

  const float4 v = reinterpret_cast<const float4*>(emb + (size_t)m * kD)[t];
  float s = v.x * v.x + v.y * v.y + v.z * v.z + v.w * v.w;
#pragma unroll
  for (int mask = 32; mask >= 1; mask >>= 1) s += __shfl_xor(s, mask);
  __shared__ float red[4];
  if ((t & 63) == 0) red[t >> 6] = s;
  __syncthreads();
  const float tot = red[0] + red[1] + red[2] + red[3];
  const float sc  = sqrtf(tot) + 1e-4f;
  const float inv = 1.0f / sc;
  const float4 nv = make_float4(v.x * inv, v.y * inv, v.z * inv, v.w * inv);

  float s2 = nv.x * nv.x + nv.y * nv.y + nv.z * nv.z + nv.w * nv.w;
#pragma unroll
  for (int mask = 32; mask >= 1; mask >>= 1) s2 += __shfl_xor(s2, mask);
  __syncthreads();
  if ((t & 63) == 0) red[t >> 6] = s2;
  __syncthreads();
  if (t == 0) {
    ws[WS_E2N + m] = red[0] + red[1] + red[2] + red[3];
    ws[WS_SCL + m] = sc;
    ws[WS_E2R + m] = tot;
  }

  // hi/lo truncation split, packed to the swizzled image
  unsigned short* imgh = (unsigned short*)(ws + WS_IMG_H);
  unsigned short* imgl = (unsigned short*)(ws + WS_IMG_L);
  const int c  = t >> 3;              // k-chunk (k = 4t..4t+3)
  const int g  = (t >> 1) & 3;        // 8-elem group within chunk
  const int sq = g ^ ((m >> 1) & 3);  // bank swizzle
  const int base = c * 8192 + m * 32 + sq * 8 + 4 * (t & 1);
  ushort4 hq, lq;
#pragma unroll
  for (int j = 0; j < 4; ++j) {
    const float fv = (&nv.x)[j];
    const unsigned int b = __float_as_uint(fv);
    const unsigned short hi = (unsigned short)(b >> 16);
    const float lof = fv - __uint_as_float(b & 0xFFFF0000u);
    const unsigned short lo = (unsigned short)(__float_as_uint(lof) >> 16);
    (&hq.x)[j] = hi; (&lq.x)[j] = lo;
  }
  *(ushort4*)(imgh + base) = hq;
  *(ushort4*)(imgl + base) = lq;
}

// ---------------- kernel 2: MFMA distances + argmin + gather + stats + finals ----
// LDS pool (80KB exactly):
//   [0,16384)      X[2]:    X[q] at q*8192 = [hi 4K][lo 4K], [64 rows][32 k]
//   [16384,81920)  bbuf[2]: bbuf[p] wave-w slice at 16384 + p*32768 + w*8192
//                           = [hi 4K][lo 4K]
// Epilogue aliases pool[0..] after loop drain.

struct Frags {
  short8 a0h, a1h, a2h, a3h, a0l, a1l, a2l, a3l;
  short8 b0h, b1h, b2h, b3h, b0l, b1l, b2l, b3l;
};

// stage wave's own 8KB B slice for chunk KCN into bbuf[P]
#define DMASTAGE(KCN, P)                                                       \
  {                                                                            \
    const unsigned short* gh_ = imgH + ((size_t)(KCN) << 13) + (w << 11) + (l << 3); \
    const unsigned short* gl_ = imgL + ((size_t)(KCN) << 13) + (w << 11) + (l << 3); \
    char* dg_ = pool + 16384 + (P) * 32768 + w * 8192;                         \
    gl2lds16(gh_,        dg_);                                                 \
    gl2lds16(gh_ +  512, dg_ + 1024);                                          \
    gl2lds16(gh_ + 1024, dg_ + 2048);                                          \
    gl2lds16(gh_ + 1536, dg_ + 3072);                                          \
    gl2lds16(gl_,        dg_ + 4096);                                          \
    gl2lds16(gl_ +  512, dg_ + 5120);                                          \
    gl2lds16(gl_ + 1024, dg_ + 6144);                                          \
    gl2lds16(gl_ + 1536, dg_ + 7168);                                          \
  }

// prefetch frags for a chunk whose parity is PN into FN (16 ds_reads)
// B immediates: 16384 + PN*32768 + [0,7168]  (max 56320 < 65536)
// A immediates: PN*8192 + [0,7168]           (max 15360)
#define PREFETCH(PN, FN)                                                       \
  (FN).b0h = ldsr<16384 + (PN) * 32768 + 0 * 1024>(pB);                        \
  (FN).b1h = ldsr<16384 + (PN) * 32768 + 1 * 1024>(pB);                        \
  (FN).b2h = ldsr<16384 + (PN) * 32768 + 2 * 1024>(pB);                        \
  (FN).b3h = ldsr<16384 + (PN) * 32768 + 3 * 1024>(pB);                        \
  (FN).b0l = ldsr<16384 + (PN) * 32768 + 4096 + 0 * 1024>(pB);                 \
  (FN).b1l = ldsr<16384 + (PN) * 32768 + 4096 + 1 * 1024>(pB);                 \
  (FN).b2l = ldsr<16384 + (PN) * 32768 + 4096 + 2 * 1024>(pB);                 \
  (FN).b3l = ldsr<16384 + (PN) * 32768 + 4096 + 3 * 1024>(pB);                 \
  (FN).a0h = ldsr<(PN) * 8192 + 0 * 1024>(pA);                                 \
  (FN).a1h = ldsr<(PN) * 8192 + 1 * 1024>(pA);                                 \
  (FN).a2h = ldsr<(PN) * 8192 + 2 * 1024>(pA);                                 \
  (FN).a3h = ldsr<(PN) * 8192 + 3 * 1024>(pA);                                 \
  (FN).a0l = ldsr<(PN) * 8192 + 4096 + 0 * 1024>(pA);                          \
  (FN).a1l = ldsr<(PN) * 8192 + 4096 + 1 * 1024>(pA);                         \
  (FN).a2l = ldsr<(PN) * 8192 + 4096 + 2 * 1024>(pA);                          \
  (FN).a3l = ldsr<(PN) * 8192 + 4096 + 3 * 1024>(pA);

// split 8 consecutive k floats (f32x4 pair) into hi/lo bf16 frags; x2 optional
#define CONV8(F0, F1, AH, AL, X2EN)                                            \
  {                                                                            \
    union { short8 v; unsigned short u[8]; } H_, L_;                           \
    _Pragma("unroll")                                                          \
    for (int jj_ = 0; jj_ < 8; ++jj_) {                                        \
      const float fv_ = (jj_ < 4) ? (F0)[jj_] : (F1)[jj_ - 4];                 \
      const unsigned int b_ = __float_as_uint(fv_);                            \
      H_.u[jj_] = (unsigned short)(b_ >> 16);                                  \
      const float lo_ = fv_ - __uint_as_float(b_ & 0xFFFF0000u);               \
      L_.u[jj_] = (unsigned short)(__float_as_uint(lo_) >> 16);                \
      if (X2EN) x2 += fv_ * fv_;                                               \
    }                                                                          \
    AH = H_.v; AL = L_.v;                                                      \
  }

#define MMQ(AR, B0, B1, B2, B3, RT)                                                        \
  acc[RT][0] = __builtin_amdgcn_mfma_f32_16x16x32_bf16(AR, B0, acc[RT][0], 0, 0, 0);       \
  acc[RT][1] = __builtin_amdgcn_mfma_f32_16x16x32_bf16(AR, B1, acc[RT][1], 0, 0, 0);       \
  acc[RT][2] = __builtin_amdgcn_mfma_f32_16x16x32_bf16(AR, B2, acc[RT][2], 0, 0, 0);       \
  acc[RT][3] = __builtin_amdgcn_mfma_f32_16x16x32_bf16(AR, B3, acc[RT][3], 0, 0, 0);
#define MMPASS(A0, A1, A2, A3, B0, B1, B2, B3)                                 \
  MMQ(A0, B0, B1, B2, B3, 0) MMQ(A1, B0, B1, B2, B3, 1)                        \
  MMQ(A2, B0, B1, B2, B3, 2) MMQ(A3, B0, B1, B2, B3, 3)

// one K-chunk. P = KC&1 (compile-time). FC = frags(KC) (in regs), FN = dest for
// frags(KC+1). XC pair holds x(KC+2) (landing), XN pair gets x(KC+3).
// Entering invariant: outstanding VMEM = [x(KC+2) (2, older), DMA(KC+1) (8)].
#define VQ_ITER7(KC, P, FC, FN, XC0, XC1, XN0, XN1)                            \
  {                                                                            \
    __builtin_amdgcn_s_setprio(1);                                             \
    MMPASS(FC.a0h, FC.a1h, FC.a2h, FC.a3h, FC.b0h, FC.b1h, FC.b2h, FC.b3h)     \
    __builtin_amdgcn_s_setprio(0);                                             \
    asm volatile("s_waitcnt vmcnt(8)" ::: "memory");   /* x(KC+2) landed */    \
    __builtin_amdgcn_sched_barrier(0);                                         \
    if ((KC) < 30) {                                                           \
      short8 cah, cal;                                                         \
      CONV8(XC0, XC1, cah, cal, 1)                                             \
      ldsw<(P) * 8192 + 0>(pW, cah);                                           \
      ldsw<(P) * 8192 + 4096>(pW, cal);                                        \
    }                                                                          \
    {                                                                          \
      const int kx_ = ((KC) + 3 < 32) ? (KC) + 3 : 31;                         \
      XN0 = gld4(xrow + kx_ * 32);                                             \
      XN1 = gld4(xrow + kx_ * 32 + 4);                                         \
      const int kb_ = ((KC) + 2 < 32) ? (KC) + 2 : 31;                         \
      DMASTAGE(kb_, P)                                                         \
    }                                                                          \
    __builtin_amdgcn_s_setprio(1);                                             \
    MMPASS(FC.a0h, FC.a1h, FC.a2h, FC.a3h, FC.b0l, FC.b1l, FC.b2l, FC.b3l)     \
    __builtin_amdgcn_s_setprio(0);                                             \
    asm volatile("s_waitcnt vmcnt(10)" ::: "memory");  /* DMA(KC+1) done */    \
    __builtin_amdgcn_sched_barrier(0);                                         \
    PREFETCH((P) ^ 1, FN)                                                      \
    __builtin_amdgcn_s_setprio(1);                                             \
    MMPASS(FC.a0l, FC.a1l, FC.a2l, FC.a3l, FC.b0h, FC.b1h, FC.b2h, FC.b3h)     \
    __builtin_amdgcn_s_setprio(0);                                             \
    asm volatile("s_waitcnt lgkmcnt(0)" ::: "memory"); /* frags(KC+1) + X writes */ \
    __builtin_amdgcn_sched_barrier(0);                                         \
    __builtin_amdgcn_s_barrier();                                              \
  }

__global__ __launch_bounds__(256, 2) void vq_main(const float* __restrict__ x,
                                                  const float* __restrict__ emb,
                                                  const float* __restrict__ wsc,
                                                  float* __restrict__ out,
                                                  float* __restrict__ commit_sum,
                                                  int* __restrict__ hist,
                                                  int* __restrict__ ticket) {
  __shared__ char pool[81920];     // exactly 80KB: 2 blocks/CU = 160KiB

  const int t   = threadIdx.x;
  const int l   = t & 63;
  const int w   = t >> 6;          // 0..3
  const int nlo = l & 15;
  const int kq  = l >> 4;          // 0..3
  const int blk0 = blockIdx.x * 64;

  const unsigned short* imgH = (const unsigned short*)(wsc + WS_IMG_H);
  const unsigned short* imgL = (const unsigned short*)(wsc + WS_IMG_L);

  // x pointer: wave w converts rows [w*16,+16): lane (nlo,kq) -> row w*16+nlo,
  // k = chunk*32 + kq*8
  const float* xrow = x + (size_t)(blk0 + w * 16 + nlo) * kD + kq * 8;

  // LDS lane bases — v2/v6's measured-conflict-free [64][32] tile pattern
  const int sqz = kq ^ ((nlo >> 1) & 3);
  lds_chc* base = (lds_chc*)pool;
  lds_chc* pA = base + nlo * 64 + sqz * 16;             // X reads (+imm)
  lds_chc* pB = base + w * 8192 + nlo * 64 + sqz * 16;  // own B slice (+16384 imm)
  lds_chc* pW = pA + w * 1024;                          // X write: row w*16+nlo

  f32x4 acc[4][4];
#pragma unroll
  for (int i = 0; i < 4; ++i)
#pragma unroll
    for (int j = 0; j < 4; ++j) acc[i][j] = (f32x4)0.0f;
  float x2 = 0.0f;

  Frags F0, F1;

  // ---- prologue: fill the 1-deep pipeline.
  // issue order: x(0)[2], x(1)[2], DMA B(0)[8]  -> outstanding 12
  f32x4 xa0 = gld4(xrow);
  f32x4 xa1 = gld4(xrow + 4);
  f32x4 xb0 = gld4(xrow + 32);
  f32x4 xb1 = gld4(xrow + 36);
  DMASTAGE(0, 0)
  asm volatile("s_waitcnt vmcnt(10)" ::: "memory");   // x(0) landed
  __builtin_amdgcn_sched_barrier(0);
  {
    short8 cah, cal;
    CONV8(xa0, xa1, cah, cal, 1)          // conv(0) -> X[0]
    ldsw<0>(pW, cah);
    ldsw<4096>(pW, cal);
  }
  asm volatile("s_waitcnt vmcnt(8)" ::: "memory");    // x(1) landed (DMA0 out)
  __builtin_amdgcn_sched_barrier(0);
  {
    short8 cah, cal;
    CONV8(xb0, xb1, cah, cal, 1)          // conv(1) -> X[1]
    ldsw<8192 + 0>(pW, cah);
    ldsw<8192 + 4096>(pW, cal);
  }
  xa0 = gld4(xrow + 2 * 32);              // x(2) -> pair A   [outstanding 10]
  xa1 = gld4(xrow + 2 * 32 + 4);
  DMASTAGE(1, 1)                          // DMA B(1)         [outstanding 18]
  asm volatile("s_waitcnt lgkmcnt(0)" ::: "memory");
  __builtin_amdgcn_sched_barrier(0);
  __builtin_amdgcn_s_barrier();           // X[0], X[1] published
  asm volatile("s_waitcnt vmcnt(10)" ::: "memory");   // DMA B(0) complete
  __builtin_amdgcn_sched_barrier(0);
  PREFETCH(0, F0)                          // frags(0)
  asm volatile("s_waitcnt lgkmcnt(0)" ::: "memory");
  __builtin_amdgcn_sched_barrier(0);
  // invariant entering loop: outstanding = [x(2)(2, older), DMA(1)(8)]

#pragma unroll 1
  for (int kk = 0; kk < 32; kk += 2) {
    VQ_ITER7(kk,     0, F0, F1, xa0, xa1, xb0, xb1)
    VQ_ITER7(kk + 1, 1, F1, F0, xb0, xb1, xa0, xa1)
  }

  // ---- drain all asm-issued VMEM before register reuse / LDS alias (v5 lesson).
  asm volatile("s_waitcnt vmcnt(0)"
               :: "v"(xa0), "v"(xa1), "v"(xb0), "v"(xb1) : "memory");

  // epilogue aliases (pool[0..2560), all LDS quiesced after final barrier)
  float* x2s  = (float*)pool;              // 64 f
  float* bvp  = x2s + 64;                  // 4*64 f
  int*   bjp  = (int*)(bvp + 256);         // 4*64 i
  int*   idxs = bjp + 256;                 // 64 i

  // ---- ||x_row||^2 for rows w*16+nlo (reduce k-quads)
  x2 += __shfl_xor(x2, 16);
  x2 += __shfl_xor(x2, 32);
  if (l < 16) x2s[w * 16 + l] = x2;

  // ---- per-wave argmin over its 64 codes.
  // acc[rt][ct][rg] at lane (nlo,kq) = dot(row rt*16+kq*4+rg, code w*64+ct*16+nlo)
  float eN[4];
#pragma unroll
  for (int ct = 0; ct < 4; ++ct) eN[ct] = wsc[WS_E2N + w * 64 + ct * 16 + nlo];

  float bv[4][4]; int bj[4][4];        // [rt][rg]
#pragma unroll
  for (int rt = 0; rt < 4; ++rt)
#pragma unroll
    for (int rg = 0; rg < 4; ++rg) { bv[rt][rg] = 3.0e38f; bj[rt][rg] = 0; }
#pragma unroll
  for (int ct = 0; ct < 4; ++ct) {
    const int j = w * 64 + ct * 16 + nlo;
#pragma unroll
    for (int rt = 0; rt < 4; ++rt)
#pragma unroll
      for (int rg = 0; rg < 4; ++rg) {
        const float v = eN[ct] - 2.0f * acc[rt][ct][rg];
        if (v < bv[rt][rg] || (v == bv[rt][rg] && j < bj[rt][rg])) {
          bv[rt][rg] = v; bj[rt][rg] = j;
        }
      }
  }
#pragma unroll
  for (int mk = 1; mk <= 8; mk <<= 1) {   // butterfly across nlo (16-group)
#pragma unroll
    for (int rt = 0; rt < 4; ++rt)
#pragma unroll
      for (int rg = 0; rg < 4; ++rg) {
        const float ov = __shfl_xor(bv[rt][rg], mk);
        const int   oj = __shfl_xor(bj[rt][rg], mk);
        if (ov < bv[rt][rg] || (ov == bv[rt][rg] && oj < bj[rt][rg])) {
          bv[rt][rg] = ov; bj[rt][rg] = oj;
        }
      }
  }
  __syncthreads();   // aliased region settled block-wide before cross-wave use
  if (nlo == 0) {
#pragma unroll
    for (int rt = 0; rt < 4; ++rt)
#pragma unroll
      for (int rg = 0; rg < 4; ++rg) {
        const int row = rt * 16 + kq * 4 + rg;
        bvp[w * 64 + row] = bv[rt][rg];
        bjp[w * 64 + row] = bj[rt][rg];
      }
  }
  __syncthreads();

  // ---- combine across waves + stats (threads 0..63 = wave 0)
  if (t < 64) {
    const int row = t;
    float v = bvp[row]; int j = bjp[row];
#pragma unroll
    for (int wv = 1; wv < 4; ++wv) {
      const float v2 = bvp[wv * 64 + row]; const int j2 = bjp[wv * 64 + row];
      if (v2 < v || (v2 == v && j2 < j)) { v = v2; j = j2; }
    }
    idxs[row] = j;
    atomicAdd(&hist[j], 1);
    // ||x - e_raw||^2 = ||x||^2 + ||e_raw||^2 - (e2n - v)*scl   [(e2n-v) = 2*dot]
    float cl = x2s[row] + wsc[WS_E2R + j] - (wsc[WS_E2N + j] - v) * wsc[WS_SCL + j];
#pragma unroll
    for (int mk = 1; mk <= 32; mk <<= 1) cl += __shfl_xor(cl, mk);
    if (t == 0) atomicAdd(commit_sum, cl);
  }
  __syncthreads();

  // ---- gather: quantized row = raw embedding[argmin]; wave w -> rows w*16..+16
  const float4* emb4 = (const float4*)emb;
  float4* out4 = (float4*)out;
#pragma unroll 2
  for (int rr = 0; rr < 16; ++rr) {
    const int j = idxs[w * 16 + rr];
    const float4* s = emb4 + (size_t)j * (kD / 4);
    float4* d = out4 + (size_t)(blk0 + w * 16 + rr) * (kD / 4);
#pragma unroll
    for (int c = 0; c < 4; ++c) d[c * 64 + l] = s[c * 64 + l];
  }

  // ---- last-finishing block computes the final scalars (folds vq_final)
  __threadfence();
  int* doneflag = (int*)(pool + 4160);
  if (t == 0) *doneflag = atomicAdd(ticket, 1);
  __syncthreads();
  if (*doneflag == (kNT / 64) - 1) {
    const int h = atomicAdd(&hist[t], 0);          // read via atomic path
    const float p = (float)h * (1.0f / (float)kNT);
    float s = p * logf(p + 1e-10f);
#pragma unroll
    for (int mask = 32; mask >= 1; mask >>= 1) s += __shfl_xor(s, mask);
    float* red = (float*)(pool + 4096);
    if ((t & 63) == 0) red[t >> 6] = s;
    __syncthreads();
    if (t == 0) {
      const float ent = red[0] + red[1] + red[2] + red[3];
      const float cs = atomicAdd(commit_sum, 0.0f);
      out[kQElems]     = cs * (1.0f / (float)kQElems);
      out[kQElems + 1] = expf(-ent);
    }
  }
}

extern "C" void kernel_launch(void* const* d_in, const int* in_sizes, int n_in,
                              void* d_out, int out_size, void* d_ws, size_t ws_size,
                              hipStream_t stream) {
  (void)in_sizes; (void)n_in; (void)out_size; (void)ws_size;
  const float* x   = (const float*)d_in[0];
  const float* emb = (const float*)d_in[1];
  float* out = (float*)d_out;
  float* ws  = (float*)d_ws;

  hipLaunchKernelGGL(vq_normalize, dim3(kM), dim3(256), 0, stream, emb, ws);
  hipLaunchKernelGGL(vq_main, dim3(kNT / 64), dim3(256), 0, stream,
                     x, emb, ws, out, ws + WS_COM, (int*)(ws + WS_HIST),
                     (int*)(ws + WS_TICKET));
}

// Round 9
// 281.020 us; speedup vs baseline: 1.0695x; 1.0695x over previous
//
#include <hip/hip_runtime.h>
#include <cstdint>
#include <cstddef>

// VQ-VAE quantization forward, MI355X/gfx950 — bf16 split-precision MFMA version.
// dot(x, e_norm) = xh*eh + xh*el + xl*eh  (3x mfma_f32_16x16x32_bf16, fp32 accum)
//
// v9 (resubmit; round-8 bench was an infra "container failed twice" error, no
// kernel evidence — protocol re-audited, no defect found).
// v9 = v8 pipeline with 48KB LDS (single B buffer) so 2 blocks/CU actually fit.
// v8's 80KB exact-fit pool was denied co-residency (occupancy 13% = 1-block cap)
// -> 2x makespan. The register prefetch already double-buffers B: per chunk,
// frags(c+1) are read into regs (lgkm-counted) BEFORE DMA(c+2) overwrites the
// single 32KB bbuf. X[2] ping-pong + one barrier/chunk unchanged.
//   pool: [0,16384) X[2] (q*8192 = [hi 4K][lo 4K]);
//         [16384,49152) bbuf (16384 + w*8192 = [hi 4K][lo 4K], wave-private)

typedef __attribute__((ext_vector_type(8))) short short8;
typedef __attribute__((ext_vector_type(4))) float f32x4;

namespace {
constexpr int kNT = 25600;           // N*T rows
constexpr int kD  = 1024;            // feature dim
constexpr int kM  = 256;             // codebook size
constexpr size_t kQElems = (size_t)kNT * kD;

// ws layout (float units). Codebook images: 32 chunks x [n=256][k=32] bf16,
// 16B sub-blocks swizzled: element idx = c*8192 + n*32 + (g ^ ((n>>1)&3))*8 + (k&7)
constexpr int WS_IMG_H = 0;                    // 262144 ushort = 131072 floats
constexpr int WS_IMG_L = 131072;               // 262144 ushort
constexpr int WS_E2N   = 262144;               // ||e_norm||^2 (256)
constexpr int WS_SCL   = WS_E2N + kM;          // ||e_raw|| + 1e-4 (256)
constexpr int WS_E2R   = WS_SCL + kM;          // ||e_raw||^2 (256)
constexpr int WS_COM   = WS_E2R + kM;          // commitment accumulator (4 floats)
constexpr int WS_HIST  = WS_COM + 4;           // histogram 256 ints
constexpr int WS_TICKET = WS_HIST + kM;        // last-block ticket (1 int)
}

typedef __attribute__((address_space(3))) unsigned int        lds_u32;
typedef const __attribute__((address_space(1))) unsigned int  glb_u32;
typedef const __attribute__((address_space(3))) char          lds_chc;

__device__ __forceinline__ void gl2lds16(const void* g, void* l) {
  __builtin_amdgcn_global_load_lds((glb_u32*)g, (lds_u32*)l, 16, 0, 0);
}

// inline-asm LDS read/write: compile-time offset immediate (16-bit unsigned);
// lgkmcnt counted manually (rule #18: counted wait + sched_barrier(0)).
template <int OFF>
__device__ __forceinline__ short8 ldsr(lds_chc* p) {
  static_assert(OFF >= 0 && OFF < 65536, "ds offset immediate");
  short8 r;
  asm volatile("ds_read_b128 %0, %1 offset:%c2" : "=v"(r) : "v"(p), "i"(OFF));
  return r;
}
template <int OFF>
__device__ __forceinline__ void ldsw(lds_chc* p, short8 v) {
  static_assert(OFF >= 0 && OFF < 65536, "ds offset immediate");
  asm volatile("ds_write_b128 %0, %1 offset:%c2" :: "v"(p), "v"(v), "i"(OFF) : "memory");
}
// asm global load: keeps x-loads out of the compiler's vmcnt bookkeeping so our
// counted waits stay exact.
__device__ __forceinline__ f32x4 gld4(const float* p) {
  f32x4 r;
  asm volatile("global_load_dwordx4 %0, %1, off" : "=v"(r) : "v"(p));
  return r;
}

// ---------------- kernel 1: normalize codebook -> swizzled bf16 hi/lo images + stats ----
__global__ __launch_bounds__(256) void vq_normalize(const float* __restrict__ emb,
                                                    float* __restrict__ ws) {
  const int m = blockIdx.x;
  const int t = threadIdx.x;

  // zero-init stats (replaces hipMemsetAsync dispatch)
  if (t == 0) ((int*)(ws + WS_HIST))[m] = 0;
  if (m == 0 && t < 4) ws[WS_COM + t] = 0.0f;
  if (m == 0 && t == 4) ((int*)(ws + WS_TICKET))[0] = 0;

  const float4 v = reinterpret_cast<const float4*>(emb + (size_t)m * kD)[t];
  float s = v.x * v.x + v.y * v.y + v.z * v.z + v.w * v.w;
#pragma unroll
  for (int mask = 32; mask >= 1; mask >>= 1) s += __shfl_xor(s, mask);
  __shared__ float red[4];
  if ((t & 63) == 0) red[t >> 6] = s;
  __syncthreads();
  const float tot = red[0] + red[1] + red[2] + red[3];
  const float sc  = sqrtf(tot) + 1e-4f;
  const float inv = 1.0f / sc;
  const float4 nv = make_float4(v.x * inv, v.y * inv, v.z * inv, v.w * inv);

  float s2 = nv.x * nv.x + nv.y * nv.y + nv.z * nv.z + nv.w * nv.w;
#pragma unroll
  for (int mask = 32; mask >= 1; mask >>= 1) s2 += __shfl_xor(s2, mask);
  __syncthreads();
  if ((t & 63) == 0) red[t >> 6] = s2;
  __syncthreads();
  if (t == 0) {
    ws[WS_E2N + m] = red[0] + red[1] + red[2] + red[3];
    ws[WS_SCL + m] = sc;
    ws[WS_E2R + m] = tot;
  }

  // hi/lo truncation split, packed to the swizzled image
  unsigned short* imgh = (unsigned short*)(ws + WS_IMG_H);
  unsigned short* imgl = (unsigned short*)(ws + WS_IMG_L);
  const int c  = t >> 3;              // k-chunk (k = 4t..4t+3)
  const int g  = (t >> 1) & 3;        // 8-elem group within chunk
  const int sq = g ^ ((m >> 1) & 3);  // bank swizzle
  const int base = c * 8192 + m * 32 + sq * 8 + 4 * (t & 1);
  ushort4 hq, lq;
#pragma unroll
  for (int j = 0; j < 4; ++j) {
    const float fv = (&nv.x)[j];
    const unsigned int b = __float_as_uint(fv);
    const unsigned short hi = (unsigned short)(b >> 16);
    const float lof = fv - __uint_as_float(b & 0xFFFF0000u);
    const unsigned short lo = (unsigned short)(__float_as_uint(lof) >> 16);
    (&hq.x)[j] = hi; (&lq.x)[j] = lo;
  }
  *(ushort4*)(imgh + base) = hq;
  *(ushort4*)(imgl + base) = lq;
}

// ---------------- kernel 2: MFMA distances + argmin + gather + stats + finals ----

struct Frags {
  short8 a0h, a1h, a2h, a3h, a0l, a1l, a2l, a3l;
  short8 b0h, b1h, b2h, b3h, b0l, b1l, b2l, b3l;
};

// stage wave's own 8KB B slice for chunk KCN into the (single) bbuf
#define DMASTAGE(KCN)                                                          \
  {                                                                            \
    const unsigned short* gh_ = imgH + ((size_t)(KCN) << 13) + (w << 11) + (l << 3); \
    const unsigned short* gl_ = imgL + ((size_t)(KCN) << 13) + (w << 11) + (l << 3); \
    char* dg_ = pool + 16384 + w * 8192;                                       \
    gl2lds16(gh_,        dg_);                                                 \
    gl2lds16(gh_ +  512, dg_ + 1024);                                          \
    gl2lds16(gh_ + 1024, dg_ + 2048);                                          \
    gl2lds16(gh_ + 1536, dg_ + 3072);                                          \
    gl2lds16(gl_,        dg_ + 4096);                                          \
    gl2lds16(gl_ +  512, dg_ + 5120);                                          \
    gl2lds16(gl_ + 1024, dg_ + 6144);                                          \
    gl2lds16(gl_ + 1536, dg_ + 7168);                                          \
  }

// prefetch frags: B from bbuf (imm 16384+[0,7168]), A from X[PN] (imm PN*8192+[0,7168])
#define PREFETCH9(PN, FN)                                                      \
  (FN).b0h = ldsr<16384 + 0 * 1024>(pB);                                       \
  (FN).b1h = ldsr<16384 + 1 * 1024>(pB);                                       \
  (FN).b2h = ldsr<16384 + 2 * 1024>(pB);                                       \
  (FN).b3h = ldsr<16384 + 3 * 1024>(pB);                                       \
  (FN).b0l = ldsr<16384 + 4096 + 0 * 1024>(pB);                                \
  (FN).b1l = ldsr<16384 + 4096 + 1 * 1024>(pB);                                \
  (FN).b2l = ldsr<16384 + 4096 + 2 * 1024>(pB);                                \
  (FN).b3l = ldsr<16384 + 4096 + 3 * 1024>(pB);                                \
  (FN).a0h = ldsr<(PN) * 8192 + 0 * 1024>(pA);                                 \
  (FN).a1h = ldsr<(PN) * 8192 + 1 * 1024>(pA);                                 \
  (FN).a2h = ldsr<(PN) * 8192 + 2 * 1024>(pA);                                 \
  (FN).a3h = ldsr<(PN) * 8192 + 3 * 1024>(pA);                                 \
  (FN).a0l = ldsr<(PN) * 8192 + 4096 + 0 * 1024>(pA);                          \
  (FN).a1l = ldsr<(PN) * 8192 + 4096 + 1 * 1024>(pA);                          \
  (FN).a2l = ldsr<(PN) * 8192 + 4096 + 2 * 1024>(pA);                          \
  (FN).a3l = ldsr<(PN) * 8192 + 4096 + 3 * 1024>(pA);

// split 8 consecutive k floats (f32x4 pair) into hi/lo bf16 frags; x2 optional
#define CONV8(F0, F1, AH, AL, X2EN)                                            \
  {                                                                            \
    union { short8 v; unsigned short u[8]; } H_, L_;                           \
    _Pragma("unroll")                                                          \
    for (int jj_ = 0; jj_ < 8; ++jj_) {                                        \
      const float fv_ = (jj_ < 4) ? (F0)[jj_] : (F1)[jj_ - 4];                 \
      const unsigned int b_ = __float_as_uint(fv_);                            \
      H_.u[jj_] = (unsigned short)(b_ >> 16);                                  \
      const float lo_ = fv_ - __uint_as_float(b_ & 0xFFFF0000u);               \
      L_.u[jj_] = (unsigned short)(__float_as_uint(lo_) >> 16);                \
      if (X2EN) x2 += fv_ * fv_;                                               \
    }                                                                          \
    AH = H_.v; AL = L_.v;                                                      \
  }

#define MMQ(AR, B0, B1, B2, B3, RT)                                                        \
  acc[RT][0] = __builtin_amdgcn_mfma_f32_16x16x32_bf16(AR, B0, acc[RT][0], 0, 0, 0);       \
  acc[RT][1] = __builtin_amdgcn_mfma_f32_16x16x32_bf16(AR, B1, acc[RT][1], 0, 0, 0);       \
  acc[RT][2] = __builtin_amdgcn_mfma_f32_16x16x32_bf16(AR, B2, acc[RT][2], 0, 0, 0);       \
  acc[RT][3] = __builtin_amdgcn_mfma_f32_16x16x32_bf16(AR, B3, acc[RT][3], 0, 0, 0);
#define MMPASS(A0, A1, A2, A3, B0, B1, B2, B3)                                 \
  MMQ(A0, B0, B1, B2, B3, 0) MMQ(A1, B0, B1, B2, B3, 1)                        \
  MMQ(A2, B0, B1, B2, B3, 2) MMQ(A3, B0, B1, B2, B3, 3)

// one K-chunk. P = KC&1. FC = frags(KC) (regs), FN = dest for frags(KC+1).
// XC = x(KC+2) (landing), XN = dest for x(KC+3).
// Entering: outstanding VMEM = [x(KC+2)(2, older), DMA(KC+1)->bbuf(8)].
#define VQ_ITER9(KC, P, FC, FN, XC0, XC1, XN0, XN1)                            \
  {                                                                            \
    __builtin_amdgcn_s_setprio(1);                                             \
    MMPASS(FC.a0h, FC.a1h, FC.a2h, FC.a3h, FC.b0h, FC.b1h, FC.b2h, FC.b3h)     \
    __builtin_amdgcn_s_setprio(0);                                             \
    asm volatile("s_waitcnt vmcnt(8)" ::: "memory");   /* x(KC+2) landed */    \
    __builtin_amdgcn_sched_barrier(0);                                         \
    if ((KC) < 30) {                                                           \
      short8 cah, cal;                                                         \
      CONV8(XC0, XC1, cah, cal, 1)                                             \
      ldsw<(P) * 8192 + 0>(pW, cah);                                           \
      ldsw<(P) * 8192 + 4096>(pW, cal);                                        \
    }                                                                          \
    {                                                                          \
      const int kx_ = ((KC) + 3 < 32) ? (KC) + 3 : 31;                         \
      XN0 = gld4(xrow + kx_ * 32);                                             \
      XN1 = gld4(xrow + kx_ * 32 + 4);                                         \
    }                                                                          \
    asm volatile("s_waitcnt vmcnt(2)" ::: "memory");   /* DMA(KC+1) done */    \
    __builtin_amdgcn_sched_barrier(0);                                         \
    PREFETCH9((P) ^ 1, FN)                             /* frags(KC+1) */       \
    __builtin_amdgcn_s_setprio(1);                                             \
    MMPASS(FC.a0h, FC.a1h, FC.a2h, FC.a3h, FC.b0l, FC.b1l, FC.b2l, FC.b3l)     \
    __builtin_amdgcn_s_setprio(0);                                             \
    asm volatile("s_waitcnt lgkmcnt(0)" ::: "memory"); /* FN reads + X writes */ \
    __builtin_amdgcn_sched_barrier(0);                                         \
    {                                                                          \
      const int kb_ = ((KC) + 2 < 32) ? (KC) + 2 : 31;                         \
      DMASTAGE(kb_)                                    /* overwrite own slice */ \
    }                                                                          \
    __builtin_amdgcn_s_setprio(1);                                             \
    MMPASS(FC.a0l, FC.a1l, FC.a2l, FC.a3l, FC.b0h, FC.b1h, FC.b2h, FC.b3h)     \
    __builtin_amdgcn_s_setprio(0);                                             \
    __builtin_amdgcn_sched_barrier(0);                                         \
    __builtin_amdgcn_s_barrier();                      /* publish X[P] */      \
  }

__global__ __launch_bounds__(256, 2) void vq_main(const float* __restrict__ x,
                                                  const float* __restrict__ emb,
                                                  const float* __restrict__ wsc,
                                                  float* __restrict__ out,
                                                  float* __restrict__ commit_sum,
                                                  int* __restrict__ hist,
                                                  int* __restrict__ ticket) {
  __shared__ char pool[49152];     // 48KB: 2 blocks/CU = 96KB of 160KiB

  const int t   = threadIdx.x;
  const int l   = t & 63;
  const int w   = t >> 6;          // 0..3
  const int nlo = l & 15;
  const int kq  = l >> 4;          // 0..3
  const int blk0 = blockIdx.x * 64;

  const unsigned short* imgH = (const unsigned short*)(wsc + WS_IMG_H);
  const unsigned short* imgL = (const unsigned short*)(wsc + WS_IMG_L);

  // x pointer: wave w converts rows [w*16,+16): lane (nlo,kq) -> row w*16+nlo,
  // k = chunk*32 + kq*8
  const float* xrow = x + (size_t)(blk0 + w * 16 + nlo) * kD + kq * 8;

  // LDS lane bases — v2/v6's measured-conflict-free [64][32] tile pattern
  const int sqz = kq ^ ((nlo >> 1) & 3);
  lds_chc* base = (lds_chc*)pool;
  lds_chc* pA = base + nlo * 64 + sqz * 16;             // X reads (+imm)
  lds_chc* pB = base + w * 8192 + nlo * 64 + sqz * 16;  // own B slice (+16384 imm)
  lds_chc* pW = pA + w * 1024;                          // X write: row w*16+nlo

  f32x4 acc[4][4];
#pragma unroll
  for (int i = 0; i < 4; ++i)
#pragma unroll
    for (int j = 0; j < 4; ++j) acc[i][j] = (f32x4)0.0f;
  float x2 = 0.0f;

  Frags F0, F1;

  // ---- prologue: fill the 1-deep pipeline.
  f32x4 xa0 = gld4(xrow);
  f32x4 xa1 = gld4(xrow + 4);             // x(0)  [2]
  f32x4 xb0 = gld4(xrow + 32);
  f32x4 xb1 = gld4(xrow + 36);            // x(1)  [4]
  DMASTAGE(0)                             // B(0)  [12]
  asm volatile("s_waitcnt vmcnt(10)" ::: "memory");   // x(0) landed
  __builtin_amdgcn_sched_barrier(0);
  {
    short8 cah, cal;
    CONV8(xa0, xa1, cah, cal, 1)          // conv(0) -> X[0]
    ldsw<0>(pW, cah);
    ldsw<4096>(pW, cal);
  }
  asm volatile("s_waitcnt vmcnt(8)" ::: "memory");    // x(1) landed
  __builtin_amdgcn_sched_barrier(0);
  {
    short8 cah, cal;
    CONV8(xb0, xb1, cah, cal, 1)          // conv(1) -> X[1]
    ldsw<8192 + 0>(pW, cah);
    ldsw<8192 + 4096>(pW, cal);
  }
  xa0 = gld4(xrow + 2 * 32);              // x(2)  [outstanding: B0(8)+x2(2)]
  xa1 = gld4(xrow + 2 * 32 + 4);
  asm volatile("s_waitcnt vmcnt(2)" ::: "memory");    // DMA B(0) complete
  __builtin_amdgcn_sched_barrier(0);
  asm volatile("s_waitcnt lgkmcnt(0)" ::: "memory");  // X writes retired
  __builtin_amdgcn_sched_barrier(0);
  __builtin_amdgcn_s_barrier();           // X[0], X[1] + bbuf(chunk0) published
  PREFETCH9(0, F0)                        // frags(0): B from bbuf, A from X[0]
  asm volatile("s_waitcnt lgkmcnt(0)" ::: "memory");
  __builtin_amdgcn_sched_barrier(0);
  DMASTAGE(1)                             // B(1) overwrite (own reads retired)
  __builtin_amdgcn_s_barrier();           // all waves' X[0]-reads retired
  // invariant entering loop: outstanding = [x(2)(2, older), DMA(1)(8)]

#pragma unroll 1
  for (int kk = 0; kk < 32; kk += 2) {
    VQ_ITER9(kk,     0, F0, F1, xa0, xa1, xb0, xb1)
    VQ_ITER9(kk + 1, 1, F1, F0, xb0, xb1, xa0, xa1)
  }

  // ---- drain all asm-issued VMEM before register reuse / LDS alias (v5 lesson).
  asm volatile("s_waitcnt vmcnt(0)"
               :: "v"(xa0), "v"(xa1), "v"(xb0), "v"(xb1) : "memory");

  // epilogue aliases (pool[0..2560) = X region; tail DMAs land at >=16384)
  float* x2s  = (float*)pool;              // 64 f
  float* bvp  = x2s + 64;                  // 4*64 f
  int*   bjp  = (int*)(bvp + 256);         // 4*64 i
  int*   idxs = bjp + 256;                 // 64 i

  // ---- ||x_row||^2 for rows w*16+nlo (reduce k-quads)
  x2 += __shfl_xor(x2, 16);
  x2 += __shfl_xor(x2, 32);
  if (l < 16) x2s[w * 16 + l] = x2;

  // ---- per-wave argmin over its 64 codes.
  // acc[rt][ct][rg] at lane (nlo,kq) = dot(row rt*16+kq*4+rg, code w*64+ct*16+nlo)
  float eN[4];
#pragma unroll
  for (int ct = 0; ct < 4; ++ct) eN[ct] = wsc[WS_E2N + w * 64 + ct * 16 + nlo];

  float bv[4][4]; int bj[4][4];        // [rt][rg]
#pragma unroll
  for (int rt = 0; rt < 4; ++rt)
#pragma unroll
    for (int rg = 0; rg < 4; ++rg) { bv[rt][rg] = 3.0e38f; bj[rt][rg] = 0; }
#pragma unroll
  for (int ct = 0; ct < 4; ++ct) {
    const int j = w * 64 + ct * 16 + nlo;
#pragma unroll
    for (int rt = 0; rt < 4; ++rt)
#pragma unroll
      for (int rg = 0; rg < 4; ++rg) {
        const float v = eN[ct] - 2.0f * acc[rt][ct][rg];
        if (v < bv[rt][rg] || (v == bv[rt][rg] && j < bj[rt][rg])) {
          bv[rt][rg] = v; bj[rt][rg] = j;
        }
      }
  }
#pragma unroll
  for (int mk = 1; mk <= 8; mk <<= 1) {   // butterfly across nlo (16-group)
#pragma unroll
    for (int rt = 0; rt < 4; ++rt)
#pragma unroll
      for (int rg = 0; rg < 4; ++rg) {
        const float ov = __shfl_xor(bv[rt][rg], mk);
        const int   oj = __shfl_xor(bj[rt][rg], mk);
        if (ov < bv[rt][rg] || (ov == bv[rt][rg] && oj < bj[rt][rg])) {
          bv[rt][rg] = ov; bj[rt][rg] = oj;
        }
      }
  }
  __syncthreads();   // aliased region settled block-wide before cross-wave use
  if (nlo == 0) {
#pragma unroll
    for (int rt = 0; rt < 4; ++rt)
#pragma unroll
      for (int rg = 0; rg < 4; ++rg) {
        const int row = rt * 16 + kq * 4 + rg;
        bvp[w * 64 + row] = bv[rt][rg];
        bjp[w * 64 + row] = bj[rt][rg];
      }
  }
  __syncthreads();

  // ---- combine across waves + stats (threads 0..63 = wave 0)
  if (t < 64) {
    const int row = t;
    float v = bvp[row]; int j = bjp[row];
#pragma unroll
    for (int wv = 1; wv < 4; ++wv) {
      const float v2 = bvp[wv * 64 + row]; const int j2 = bjp[wv * 64 + row];
      if (v2 < v || (v2 == v && j2 < j)) { v = v2; j = j2; }
    }
    idxs[row] = j;
    atomicAdd(&hist[j], 1);
    // ||x - e_raw||^2 = ||x||^2 + ||e_raw||^2 - (e2n - v)*scl   [(e2n-v) = 2*dot]
    float cl = x2s[row] + wsc[WS_E2R + j] - (wsc[WS_E2N + j] - v) * wsc[WS_SCL + j];
#pragma unroll
    for (int mk = 1; mk <= 32; mk <<= 1) cl += __shfl_xor(cl, mk);
    if (t == 0) atomicAdd(commit_sum, cl);
  }
  __syncthreads();

  // ---- gather: quantized row = raw embedding[argmin]; wave w -> rows w*16..+16
  const float4* emb4 = (const float4*)emb;
  float4* out4 = (float4*)out;
#pragma unroll 2
  for (int rr = 0; rr < 16; ++rr) {
    const int j = idxs[w * 16 + rr];
    const float4* s = emb4 + (size_t)j * (kD / 4);
    float4* d = out4 + (size_t)(blk0 + w * 16 + rr) * (kD / 4);
#pragma unroll
    for (int c = 0; c < 4; ++c) d[c * 64 + l] = s[c * 64 + l];
  }

  // ---- last-finishing block computes the final scalars (folds vq_final)
  __threadfence();
  int* doneflag = (int*)(pool + 4160);
  if (t == 0) *doneflag = atomicAdd(ticket, 1);
  __syncthreads();
  if (*doneflag == (kNT / 64) - 1) {
    const int h = atomicAdd(&hist[t], 0);          // read via atomic path
    const float p = (float)h * (1.0f / (float)kNT);
    float s = p * logf(p + 1e-10f);
#pragma unroll
    for (int mask = 32; mask >= 1; mask >>= 1) s += __shfl_xor(s, mask);
    float* red = (float*)(pool + 4096);
    if ((t & 63) == 0) red[t >> 6] = s;
    __syncthreads();
    if (t == 0) {
      const float ent = red[0] + red[1] + red[2] + red[3];
      const float cs = atomicAdd(commit_sum, 0.0f);
      out[kQElems]     = cs * (1.0f / (float)kQElems);
      out[kQElems + 1] = expf(-ent);
    }
  }
}

extern "C" void kernel_launch(void* const* d_in, const int* in_sizes, int n_in,
                              void* d_out, int out_size, void* d_ws, size_t ws_size,
                              hipStream_t stream) {
  (void)in_sizes; (void)n_in; (void)out_size; (void)ws_size;
  const float* x   = (const float*)d_in[0];
  const float* emb = (const float*)d_in[1];
  float* out = (float*)d_out;
  float* ws  = (float*)d_ws;

  hipLaunchKernelGGL(vq_normalize, dim3(kM), dim3(256), 0, stream, emb, ws);
  hipLaunchKernelGGL(vq_main, dim3(kNT / 64), dim3(256), 0, stream,
                     x, emb, ws, out, ws + WS_COM, (int*)(ws + WS_HIST),
                     (int*)(ws + WS_TICKET));
}